// Round 2
// baseline (118997.705 us; speedup 1.0000x reference)
//
#include <hip/hip_runtime.h>

// ForexLSTM: 2-layer LSTM (B=1024, T=512, D=14, H=128) + batchnorm-over-batch + MLP(128->32->1)
//
// Strategy (round 1): fully fused scan kernel. 256 blocks x 256 threads, 4 batches/block.
// All three 512x128 weight matrices live in REGISTERS as f16 (2 gate-rows per thread,
// 384 VGPRs of weights), dots via v_dot2_f32_f16 (fp32 accumulate). Hidden state f16 in
// LDS, cell state fp32 in registers. No intermediate tensors in HBM except the final
// h2[:, -1, :] (512 KB in d_ws).

#define B_ 1024
#define T_ 512
#define D_ 14
#define H_ 128
#define G_ 512   // 4*H
#define NB 4     // batches per block
#define NT 256   // threads per block

typedef _Float16 f16;
typedef _Float16 f16x2 __attribute__((ext_vector_type(2)));
typedef _Float16 f16x8 __attribute__((ext_vector_type(8)));

union f16x8u { f16x8 v; f16x2 p[4]; };

__device__ __forceinline__ float dot2f(f16x2 a, f16x2 b, float c) {
#if __has_builtin(__builtin_amdgcn_fdot2)
    return __builtin_amdgcn_fdot2(a, b, c, false);
#else
    return c + (float)a[0] * (float)b[0] + (float)a[1] * (float)b[1];
#endif
}

__device__ __forceinline__ float fexp(float x) {
    return __builtin_amdgcn_exp2f(x * 1.44269504088896f);
}
__device__ __forceinline__ float sigm(float x) {
    return __builtin_amdgcn_rcpf(1.0f + fexp(-x));
}
__device__ __forceinline__ float tanh_(float x) {
    // tanh(x) = 1 - 2/(exp(2x)+1)
    return 1.0f - 2.0f * __builtin_amdgcn_rcpf(1.0f + fexp(2.0f * x));
}

__global__ __launch_bounds__(NT, 1) void lstm_fused(
    const float* __restrict__ x,
    const float* __restrict__ Wih0, const float* __restrict__ Whh0,
    const float* __restrict__ bih0, const float* __restrict__ bhh0,
    const float* __restrict__ Wih1, const float* __restrict__ Whh1,
    const float* __restrict__ bih1, const float* __restrict__ bhh1,
    float* __restrict__ h2last)
{
    __shared__ __align__(16) f16 hA[NB][H_];        // layer-0 hidden (f16)
    __shared__ __align__(16) f16 hB[NB][H_];        // layer-1 hidden (f16)
    __shared__ __align__(16) float gact[NB][G_];    // activated gates exchange (8 KB)
    __shared__ __align__(16) f16 xs[2][NB][16];     // x staging, double-buffered, padded 14->16

    const int tid = threadIdx.x;
    const int b0 = blockIdx.x * NB;

    // ---- load weights into registers (rows r0=tid, r1=tid+256) ----
    f16x2 wA[2][64];   // Whh0 rows
    f16x2 wI[2][64];   // Wih1 rows
    f16x2 wR[2][64];   // Whh1 rows
    f16x2 w0p[2][8];   // Wih0 rows (14 padded to 16)
    float bias0[2], bias1[2];

#pragma unroll
    for (int s = 0; s < 2; ++s) {
        const int r = tid + s * 256;
        const float* pA = Whh0 + (size_t)r * H_;
        const float* pI = Wih1 + (size_t)r * H_;
        const float* pR = Whh1 + (size_t)r * H_;
#pragma unroll
        for (int k = 0; k < 64; ++k) {
            f16x2 a; a[0] = (f16)pA[2 * k]; a[1] = (f16)pA[2 * k + 1]; wA[s][k] = a;
            f16x2 i_; i_[0] = (f16)pI[2 * k]; i_[1] = (f16)pI[2 * k + 1]; wI[s][k] = i_;
            f16x2 rr; rr[0] = (f16)pR[2 * k]; rr[1] = (f16)pR[2 * k + 1]; wR[s][k] = rr;
        }
        const float* p0 = Wih0 + (size_t)r * D_;
#pragma unroll
        for (int q = 0; q < 8; ++q) {
            f16x2 w;
            w[0] = (2 * q     < D_) ? (f16)p0[2 * q]     : (f16)0.0f;
            w[1] = (2 * q + 1 < D_) ? (f16)p0[2 * q + 1] : (f16)0.0f;
            w0p[s][q] = w;
        }
        bias0[s] = bih0[r] + bhh0[r];
        bias1[s] = bih1[r] + bhh1[r];
    }

    // ---- init LDS state ----
#pragma unroll
    for (int s = 0; s < 2; ++s) {
        int m = tid + s * 256;
        int b = m >> 7, j = m & 127;
        hA[b][j] = (f16)0.0f;
        hB[b][j] = (f16)0.0f;
    }
    if (tid < 64) {
        int b = tid >> 4, d = tid & 15;
        float v = 0.0f;
        if (d < D_) v = x[((size_t)(b0 + b) * T_ + 0) * D_ + d];
        xs[0][b][d] = (f16)v;
        xs[1][b][d] = (f16)0.0f;
    }

    float cA[2] = {0.0f, 0.0f}, cB[2] = {0.0f, 0.0f};
    // update-phase mapping: m = tid + 256*s -> (b, j)
    const int um_b0 = tid >> 7;            // s=0 -> b in {0,1}
    const int um_b1 = (tid >> 7) + 2;      // s=1 -> b in {2,3}
    const int um_j = tid & 127;
    const bool is_tanh_row = (tid < 128);  // r1 row type: g(tanh) if tid<128 else o(sigmoid)
    // x prefetch mapping
    const int pb = tid / D_, pd = tid - pb * D_;
    const bool do_pref = (tid < NB * D_);

    __syncthreads();

    for (int t = 0; t < T_; ++t) {
        const int cur = t & 1, nxt = cur ^ 1;

        // prefetch next step's x (hidden under compute)
        float xpre = 0.0f;
        if (do_pref && (t + 1) < T_)
            xpre = x[((size_t)(b0 + pb) * T_ + (t + 1)) * D_ + pd];

        // ======== phase A: layer-0 gates ========
        float acc[2][NB];
#pragma unroll
        for (int s = 0; s < 2; ++s)
#pragma unroll
            for (int b = 0; b < NB; ++b) acc[s][b] = bias0[s];

        // input projection (x part, f16 dot2)
#pragma unroll
        for (int b = 0; b < NB; ++b) {
            f16x8u xv0, xv1;
            xv0.v = *(const f16x8*)&xs[cur][b][0];
            xv1.v = *(const f16x8*)&xs[cur][b][8];
#pragma unroll
            for (int q = 0; q < 4; ++q) {
#pragma unroll
                for (int s = 0; s < 2; ++s) {
                    acc[s][b] = dot2f(w0p[s][q], xv0.p[q], acc[s][b]);
                    acc[s][b] = dot2f(w0p[s][q + 4], xv1.p[q], acc[s][b]);
                }
            }
        }
        // recurrent: Whh0 . hA_prev
#pragma unroll
        for (int kc8 = 0; kc8 < 16; ++kc8) {
            f16x8u hv[NB];
#pragma unroll
            for (int b = 0; b < NB; ++b)
                hv[b].v = *(const f16x8*)&hA[b][kc8 * 8];
#pragma unroll
            for (int q = 0; q < 4; ++q) {
#pragma unroll
                for (int b = 0; b < NB; ++b) {
#pragma unroll
                    for (int s = 0; s < 2; ++s)
                        acc[s][b] = dot2f(wA[s][kc8 * 4 + q], hv[b].p[q], acc[s][b]);
                }
            }
        }
        // activations -> gact  (r0: i/f -> sigmoid; r1: g -> tanh (tid<128) else o -> sigmoid)
#pragma unroll
        for (int b = 0; b < NB; ++b) {
            gact[b][tid] = sigm(acc[0][b]);
            gact[b][tid + 256] = is_tanh_row ? tanh_(acc[1][b]) : sigm(acc[1][b]);
        }
        __syncthreads();

        // ======== phase B: layer-0 state update ========
        {
            float iv = gact[um_b0][um_j], fv = gact[um_b0][um_j + 128];
            float gv = gact[um_b0][um_j + 256], ov = gact[um_b0][um_j + 384];
            float c = fv * cA[0] + iv * gv;
            cA[0] = c;
            hA[um_b0][um_j] = (f16)(ov * tanh_(c));
        }
        {
            float iv = gact[um_b1][um_j], fv = gact[um_b1][um_j + 128];
            float gv = gact[um_b1][um_j + 256], ov = gact[um_b1][um_j + 384];
            float c = fv * cA[1] + iv * gv;
            cA[1] = c;
            hA[um_b1][um_j] = (f16)(ov * tanh_(c));
        }
        __syncthreads();

        // ======== phase C: layer-1 gates ========
#pragma unroll
        for (int s = 0; s < 2; ++s)
#pragma unroll
            for (int b = 0; b < NB; ++b) acc[s][b] = bias1[s];

#pragma unroll
        for (int kc8 = 0; kc8 < 16; ++kc8) {
            f16x8u ha[NB], hb[NB];
#pragma unroll
            for (int b = 0; b < NB; ++b) {
                ha[b].v = *(const f16x8*)&hA[b][kc8 * 8];   // h1_t (just updated)
                hb[b].v = *(const f16x8*)&hB[b][kc8 * 8];   // h2_{t-1}
            }
#pragma unroll
            for (int q = 0; q < 4; ++q) {
#pragma unroll
                for (int b = 0; b < NB; ++b) {
#pragma unroll
                    for (int s = 0; s < 2; ++s) {
                        acc[s][b] = dot2f(wI[s][kc8 * 4 + q], ha[b].p[q], acc[s][b]);
                        acc[s][b] = dot2f(wR[s][kc8 * 4 + q], hb[b].p[q], acc[s][b]);
                    }
                }
            }
        }
#pragma unroll
        for (int b = 0; b < NB; ++b) {
            gact[b][tid] = sigm(acc[0][b]);
            gact[b][tid + 256] = is_tanh_row ? tanh_(acc[1][b]) : sigm(acc[1][b]);
        }
        __syncthreads();

        // ======== phase D: layer-1 state update (+ x stage, + final output) ========
        {
            float iv = gact[um_b0][um_j], fv = gact[um_b0][um_j + 128];
            float gv = gact[um_b0][um_j + 256], ov = gact[um_b0][um_j + 384];
            float c = fv * cB[0] + iv * gv;
            cB[0] = c;
            float h = ov * tanh_(c);
            hB[um_b0][um_j] = (f16)h;
            if (t == T_ - 1) h2last[(size_t)(b0 + um_b0) * H_ + um_j] = h;
        }
        {
            float iv = gact[um_b1][um_j], fv = gact[um_b1][um_j + 128];
            float gv = gact[um_b1][um_j + 256], ov = gact[um_b1][um_j + 384];
            float c = fv * cB[1] + iv * gv;
            cB[1] = c;
            float h = ov * tanh_(c);
            hB[um_b1][um_j] = (f16)h;
            if (t == T_ - 1) h2last[(size_t)(b0 + um_b1) * H_ + um_j] = h;
        }
        if (do_pref && (t + 1) < T_) xs[nxt][pb][pd] = (f16)xpre;
        __syncthreads();
    }
}

// batch-norm statistics over the batch dim: 1 block, 1024 threads
__global__ void bn_stats(const float* __restrict__ h2last, float* __restrict__ stats)
{
    __shared__ float red[2][8][128];
    const int tid = threadIdx.x;
    const int j = tid & 127, bs = tid >> 7;
    float s = 0.0f, ss = 0.0f;
    for (int bb = 0; bb < 128; ++bb) {
        float v = h2last[(size_t)(bb * 8 + bs) * H_ + j];
        s += v;
        ss += v * v;
    }
    red[0][bs][j] = s;
    red[1][bs][j] = ss;
    __syncthreads();
    if (tid < 128) {
        float S = 0.0f, SS = 0.0f;
#pragma unroll
        for (int k = 0; k < 8; ++k) { S += red[0][k][tid]; SS += red[1][k][tid]; }
        float mu = S * (1.0f / 1024.0f);
        float var = SS * (1.0f / 1024.0f) - mu * mu;
        stats[tid] = mu;
        stats[128 + tid] = __builtin_amdgcn_rsqf(var + 1e-5f);
    }
}

// normalize + MLP head: 8 blocks x 128 threads, one batch element per thread
__global__ void bn_mlp(const float* __restrict__ h2last, const float* __restrict__ stats,
                       const float* __restrict__ gamma, const float* __restrict__ beta,
                       const float* __restrict__ W1, const float* __restrict__ b1,
                       const float* __restrict__ W2, const float* __restrict__ b2,
                       float* __restrict__ out)
{
    __shared__ float W1T[128][33];  // transposed W1 for contiguous per-j reads
    __shared__ float mus[128], isds[128], gs[128], bts[128], w2s[32];
    const int tid = threadIdx.x;
    const int b = blockIdx.x * 128 + tid;

    for (int i = tid; i < 4096; i += 128) {
        int k = i >> 7, j = i & 127;
        W1T[j][k] = W1[i];
    }
    mus[tid] = stats[tid];
    isds[tid] = stats[128 + tid];
    gs[tid] = gamma[tid];
    bts[tid] = beta[tid];
    if (tid < 32) w2s[tid] = W2[tid];
    __syncthreads();

    float z[32];
#pragma unroll
    for (int k = 0; k < 32; ++k) z[k] = b1[k];

    for (int j = 0; j < 128; ++j) {
        float nv = (h2last[(size_t)b * H_ + j] - mus[j]) * isds[j] * gs[j] + bts[j];
#pragma unroll
        for (int k = 0; k < 32; ++k) z[k] += W1T[j][k] * nv;
    }
    float o = b2[0];
#pragma unroll
    for (int k = 0; k < 32; ++k) o += w2s[k] * fmaxf(z[k], 0.0f);
    out[b] = o;
}

extern "C" void kernel_launch(void* const* d_in, const int* in_sizes, int n_in,
                              void* d_out, int out_size, void* d_ws, size_t ws_size,
                              hipStream_t stream)
{
    const float* x    = (const float*)d_in[0];
    const float* Wih0 = (const float*)d_in[1];
    const float* Whh0 = (const float*)d_in[2];
    const float* bih0 = (const float*)d_in[3];
    const float* bhh0 = (const float*)d_in[4];
    const float* Wih1 = (const float*)d_in[5];
    const float* Whh1 = (const float*)d_in[6];
    const float* bih1 = (const float*)d_in[7];
    const float* bhh1 = (const float*)d_in[8];
    const float* gamma = (const float*)d_in[9];
    const float* beta  = (const float*)d_in[10];
    const float* W1 = (const float*)d_in[11];
    const float* b1 = (const float*)d_in[12];
    const float* W2 = (const float*)d_in[13];
    const float* b2 = (const float*)d_in[14];

    float* h2last = (float*)d_ws;              // 1024*128 floats = 512 KB
    float* stats  = h2last + (size_t)B_ * H_;  // 256 floats (mu, inv-std)
    float* out = (float*)d_out;

    hipLaunchKernelGGL(lstm_fused, dim3(B_ / NB), dim3(NT), 0, stream,
                       x, Wih0, Whh0, bih0, bhh0, Wih1, Whh1, bih1, bhh1, h2last);
    hipLaunchKernelGGL(bn_stats, dim3(1), dim3(1024), 0, stream, h2last, stats);
    hipLaunchKernelGGL(bn_mlp, dim3(8), dim3(128), 0, stream,
                       h2last, stats, gamma, beta, W1, b1, W2, b2, out);
}

// Round 3
// 108573.059 us; speedup vs baseline: 1.0960x; 1.0960x over previous
//
#include <hip/hip_runtime.h>

// ForexLSTM: 2-layer LSTM (B=1024, T=512, D=14, H=128) + batchnorm-over-batch + MLP(128->32->1)
//
// Round 2: fix R1's VGPR-spill catastrophe (50 GB scratch traffic).
// 256 blocks x 512 threads, 4 batches/block, ONE gate-row per thread:
// weights = 3*64 f16x2 = 192 VGPRs + 8 (Wih0) -> fits under the 256-VGPR cap
// required for 8 waves/CU (__launch_bounds__(512,2)). Hidden state f16 in LDS,
// cell state fp32 in registers (1 per layer per thread).

#define B_ 1024
#define T_ 512
#define D_ 14
#define H_ 128
#define G_ 512   // 4*H
#define NB 4     // batches per block
#define NT 512   // threads per block (= G_, one gate row per thread)

typedef _Float16 f16;
typedef _Float16 f16x2 __attribute__((ext_vector_type(2)));
typedef _Float16 f16x8 __attribute__((ext_vector_type(8)));

union f16x8u { f16x8 v; f16x2 p[4]; };

__device__ __forceinline__ float dot2f(f16x2 a, f16x2 b, float c) {
#if __has_builtin(__builtin_amdgcn_fdot2)
    return __builtin_amdgcn_fdot2(a, b, c, false);
#else
    return c + (float)a[0] * (float)b[0] + (float)a[1] * (float)b[1];
#endif
}

__device__ __forceinline__ float fexp(float x) {
    return __builtin_amdgcn_exp2f(x * 1.44269504088896f);
}
__device__ __forceinline__ float sigm(float x) {
    return __builtin_amdgcn_rcpf(1.0f + fexp(-x));
}
__device__ __forceinline__ float tanh_(float x) {
    return 1.0f - 2.0f * __builtin_amdgcn_rcpf(1.0f + fexp(2.0f * x));
}

__global__ __launch_bounds__(NT, 2) void lstm_fused(
    const float* __restrict__ x,
    const float* __restrict__ Wih0, const float* __restrict__ Whh0,
    const float* __restrict__ bih0, const float* __restrict__ bhh0,
    const float* __restrict__ Wih1, const float* __restrict__ Whh1,
    const float* __restrict__ bih1, const float* __restrict__ bhh1,
    float* __restrict__ h2last)
{
    __shared__ __align__(16) f16 hA[NB][H_];        // layer-0 hidden (f16)
    __shared__ __align__(16) f16 hB[NB][H_];        // layer-1 hidden (f16)
    __shared__ __align__(16) float gact[NB][G_];    // activated gates exchange (8 KB)
    __shared__ __align__(16) f16 xs[2][NB][16];     // x staging, double-buffered, padded 14->16

    const int tid = threadIdx.x;     // 0..511 == gate row r
    const int b0 = blockIdx.x * NB;
    const int r = tid;

    // ---- load this thread's weight row into registers (f16) ----
    f16x2 wA[64];   // Whh0 row r
    f16x2 wI[64];   // Wih1 row r
    f16x2 wR[64];   // Whh1 row r
    f16x2 w0p[8];   // Wih0 row r (14 padded to 16)

    {
        const float* pA = Whh0 + (size_t)r * H_;
        const float* pI = Wih1 + (size_t)r * H_;
        const float* pR = Whh1 + (size_t)r * H_;
#pragma unroll
        for (int k = 0; k < 64; ++k) {
            f16x2 a; a[0] = (f16)pA[2 * k]; a[1] = (f16)pA[2 * k + 1]; wA[k] = a;
            f16x2 i_; i_[0] = (f16)pI[2 * k]; i_[1] = (f16)pI[2 * k + 1]; wI[k] = i_;
            f16x2 rr; rr[0] = (f16)pR[2 * k]; rr[1] = (f16)pR[2 * k + 1]; wR[k] = rr;
        }
        const float* p0 = Wih0 + (size_t)r * D_;
#pragma unroll
        for (int q = 0; q < 8; ++q) {
            f16x2 w;
            w[0] = (2 * q     < D_) ? (f16)p0[2 * q]     : (f16)0.0f;
            w[1] = (2 * q + 1 < D_) ? (f16)p0[2 * q + 1] : (f16)0.0f;
            w0p[q] = w;
        }
    }
    const float bias0 = bih0[r] + bhh0[r];
    const float bias1 = bih1[r] + bhh1[r];

    // ---- init LDS state (512 threads cover NB*H = 512 states exactly) ----
    {
        int b = tid >> 7, j = tid & 127;
        hA[b][j] = (f16)0.0f;
        hB[b][j] = (f16)0.0f;
    }
    if (tid < 64) {
        int b = tid >> 4, d = tid & 15;
        float v = 0.0f;
        if (d < D_) v = x[((size_t)(b0 + b) * T_ + 0) * D_ + d];
        xs[0][b][d] = (f16)v;
        xs[1][b][d] = (f16)0.0f;
    }

    float cA = 0.0f, cB = 0.0f;
    const int um_b = tid >> 7;             // state mapping: thread <-> (b, j)
    const int um_j = tid & 127;
    const bool is_tanh_row = ((tid >> 7) == 2);  // rows 256..383 are g-gate (tanh)
    // x prefetch mapping
    const int pb = tid / D_, pd = tid - pb * D_;
    const bool do_pref = (tid < NB * D_);

    __syncthreads();

    for (int t = 0; t < T_; ++t) {
        const int cur = t & 1, nxt = cur ^ 1;

        // prefetch next step's x (hidden under compute)
        float xpre = 0.0f;
        if (do_pref && (t + 1) < T_)
            xpre = x[((size_t)(b0 + pb) * T_ + (t + 1)) * D_ + pd];

        // ======== phase A: layer-0 gates (row r, 4 batches) ========
        float acc[NB];
#pragma unroll
        for (int b = 0; b < NB; ++b) acc[b] = bias0;

        // input projection
#pragma unroll
        for (int b = 0; b < NB; ++b) {
            f16x8u xv0, xv1;
            xv0.v = *(const f16x8*)&xs[cur][b][0];
            xv1.v = *(const f16x8*)&xs[cur][b][8];
#pragma unroll
            for (int q = 0; q < 4; ++q) {
                acc[b] = dot2f(w0p[q], xv0.p[q], acc[b]);
                acc[b] = dot2f(w0p[q + 4], xv1.p[q], acc[b]);
            }
        }
        // recurrent: Whh0 . hA_prev (wave-broadcast LDS reads)
#pragma unroll
        for (int kc8 = 0; kc8 < 16; ++kc8) {
            f16x8u hv[NB];
#pragma unroll
            for (int b = 0; b < NB; ++b)
                hv[b].v = *(const f16x8*)&hA[b][kc8 * 8];
#pragma unroll
            for (int q = 0; q < 4; ++q) {
#pragma unroll
                for (int b = 0; b < NB; ++b)
                    acc[b] = dot2f(wA[kc8 * 4 + q], hv[b].p[q], acc[b]);
            }
        }
        // activation -> gact (uniform per wave: type boundary at multiples of 128)
#pragma unroll
        for (int b = 0; b < NB; ++b)
            gact[b][tid] = is_tanh_row ? tanh_(acc[b]) : sigm(acc[b]);
        __syncthreads();

        // ======== phase B: layer-0 state update (1 state per thread) ========
        {
            float iv = gact[um_b][um_j], fv = gact[um_b][um_j + 128];
            float gv = gact[um_b][um_j + 256], ov = gact[um_b][um_j + 384];
            float c = fv * cA + iv * gv;
            cA = c;
            hA[um_b][um_j] = (f16)(ov * tanh_(c));
        }
        __syncthreads();

        // ======== phase C: layer-1 gates ========
#pragma unroll
        for (int b = 0; b < NB; ++b) acc[b] = bias1;

#pragma unroll
        for (int kc8 = 0; kc8 < 16; ++kc8) {
            f16x8u ha[NB], hb[NB];
#pragma unroll
            for (int b = 0; b < NB; ++b) {
                ha[b].v = *(const f16x8*)&hA[b][kc8 * 8];   // h1_t (just updated)
                hb[b].v = *(const f16x8*)&hB[b][kc8 * 8];   // h2_{t-1}
            }
#pragma unroll
            for (int q = 0; q < 4; ++q) {
#pragma unroll
                for (int b = 0; b < NB; ++b) {
                    acc[b] = dot2f(wI[kc8 * 4 + q], ha[b].p[q], acc[b]);
                    acc[b] = dot2f(wR[kc8 * 4 + q], hb[b].p[q], acc[b]);
                }
            }
        }
#pragma unroll
        for (int b = 0; b < NB; ++b)
            gact[b][tid] = is_tanh_row ? tanh_(acc[b]) : sigm(acc[b]);
        __syncthreads();

        // ======== phase D: layer-1 state update (+ x stage, + final output) ========
        {
            float iv = gact[um_b][um_j], fv = gact[um_b][um_j + 128];
            float gv = gact[um_b][um_j + 256], ov = gact[um_b][um_j + 384];
            float c = fv * cB + iv * gv;
            cB = c;
            float h = ov * tanh_(c);
            hB[um_b][um_j] = (f16)h;
            if (t == T_ - 1) h2last[(size_t)(b0 + um_b) * H_ + um_j] = h;
        }
        if (do_pref && (t + 1) < T_) xs[nxt][pb][pd] = (f16)xpre;
        __syncthreads();
    }
}

// batch-norm statistics over the batch dim: 1 block, 1024 threads
__global__ void bn_stats(const float* __restrict__ h2last, float* __restrict__ stats)
{
    __shared__ float red[2][8][128];
    const int tid = threadIdx.x;
    const int j = tid & 127, bs = tid >> 7;
    float s = 0.0f, ss = 0.0f;
    for (int bb = 0; bb < 128; ++bb) {
        float v = h2last[(size_t)(bb * 8 + bs) * H_ + j];
        s += v;
        ss += v * v;
    }
    red[0][bs][j] = s;
    red[1][bs][j] = ss;
    __syncthreads();
    if (tid < 128) {
        float S = 0.0f, SS = 0.0f;
#pragma unroll
        for (int k = 0; k < 8; ++k) { S += red[0][k][tid]; SS += red[1][k][tid]; }
        float mu = S * (1.0f / 1024.0f);
        float var = SS * (1.0f / 1024.0f) - mu * mu;
        stats[tid] = mu;
        stats[128 + tid] = __builtin_amdgcn_rsqf(var + 1e-5f);
    }
}

// normalize + MLP head: 8 blocks x 128 threads, one batch element per thread
__global__ void bn_mlp(const float* __restrict__ h2last, const float* __restrict__ stats,
                       const float* __restrict__ gamma, const float* __restrict__ beta,
                       const float* __restrict__ W1, const float* __restrict__ b1,
                       const float* __restrict__ W2, const float* __restrict__ b2,
                       float* __restrict__ out)
{
    __shared__ float W1T[128][33];  // transposed W1 for contiguous per-j reads
    __shared__ float mus[128], isds[128], gs[128], bts[128], w2s[32];
    const int tid = threadIdx.x;
    const int b = blockIdx.x * 128 + tid;

    for (int i = tid; i < 4096; i += 128) {
        int k = i >> 7, j = i & 127;
        W1T[j][k] = W1[i];
    }
    mus[tid] = stats[tid];
    isds[tid] = stats[128 + tid];
    gs[tid] = gamma[tid];
    bts[tid] = beta[tid];
    if (tid < 32) w2s[tid] = W2[tid];
    __syncthreads();

    float z[32];
#pragma unroll
    for (int k = 0; k < 32; ++k) z[k] = b1[k];

    for (int j = 0; j < 128; ++j) {
        float nv = (h2last[(size_t)b * H_ + j] - mus[j]) * isds[j] * gs[j] + bts[j];
#pragma unroll
        for (int k = 0; k < 32; ++k) z[k] += W1T[j][k] * nv;
    }
    float o = b2[0];
#pragma unroll
    for (int k = 0; k < 32; ++k) o += w2s[k] * fmaxf(z[k], 0.0f);
    out[b] = o;
}

extern "C" void kernel_launch(void* const* d_in, const int* in_sizes, int n_in,
                              void* d_out, int out_size, void* d_ws, size_t ws_size,
                              hipStream_t stream)
{
    const float* x    = (const float*)d_in[0];
    const float* Wih0 = (const float*)d_in[1];
    const float* Whh0 = (const float*)d_in[2];
    const float* bih0 = (const float*)d_in[3];
    const float* bhh0 = (const float*)d_in[4];
    const float* Wih1 = (const float*)d_in[5];
    const float* Whh1 = (const float*)d_in[6];
    const float* bih1 = (const float*)d_in[7];
    const float* bhh1 = (const float*)d_in[8];
    const float* gamma = (const float*)d_in[9];
    const float* beta  = (const float*)d_in[10];
    const float* W1 = (const float*)d_in[11];
    const float* b1 = (const float*)d_in[12];
    const float* W2 = (const float*)d_in[13];
    const float* b2 = (const float*)d_in[14];

    float* h2last = (float*)d_ws;              // 1024*128 floats = 512 KB
    float* stats  = h2last + (size_t)B_ * H_;  // 256 floats (mu, inv-std)
    float* out = (float*)d_out;

    hipLaunchKernelGGL(lstm_fused, dim3(B_ / NB), dim3(NT), 0, stream,
                       x, Wih0, Whh0, bih0, bhh0, Wih1, Whh1, bih1, bhh1, h2last);
    hipLaunchKernelGGL(bn_stats, dim3(1), dim3(1024), 0, stream, h2last, stats);
    hipLaunchKernelGGL(bn_mlp, dim3(8), dim3(128), 0, stream,
                       h2last, stats, gamma, beta, W1, b1, W2, b2, out);
}

// Round 4
// 1320.261 us; speedup vs baseline: 90.1319x; 82.2360x over previous
//
#include <hip/hip_runtime.h>

// ForexLSTM: 2-layer LSTM (B=1024, T=512, D=14, H=128) + batchnorm-over-batch + MLP(128->32->1)
//
// Round 3: MFMA restructure. R1/R2 died on VGPR spills (compiler caps at 128 regs
// for 16 waves/CU). New design fits under 128 VGPRs/thread:
//   - 256 blocks x 1024 threads (16 waves), NB=4 batches/block.
//   - Gates via v_mfma_f32_16x16x32_f16: each wave owns 2 n-tiles (32 gate cols).
//     B-fragments in registers: Whh0(32) + Wih0(8) + Wih1(32) + Whh1 kt0-2(24) = 96 VGPRs.
//     Whh1 kt3 fragments live in LDS (32 KB) as manual register relief.
//   - h1/h2 state kept in LDS in A-fragment layout (A[m=lane&15][k=quad*8+j]),
//     written as f16 by state-update threads, read conflict-free via b128.
//   - C/D layout: col=lane&15, row=quad*4+reg (quad0 lanes hold batches 0..3).
//   - Preacts exchanged via LDS gpre[4][512] f32; threads 0-511 do act+state update
//     (1 (b,j) state per thread, c-state fp32 in registers).

#define B_ 1024
#define T_ 512
#define D_ 14
#define H_ 128
#define NB 4
#define NT 1024

typedef _Float16 f16;
typedef _Float16 half8 __attribute__((ext_vector_type(8)));
typedef float floatx4 __attribute__((ext_vector_type(4)));

__device__ __forceinline__ float fexp(float x) {
    return __builtin_amdgcn_exp2f(x * 1.44269504088896f);
}
__device__ __forceinline__ float sigm(float x) {
    return __builtin_amdgcn_rcpf(1.0f + fexp(-x));
}
__device__ __forceinline__ float tanh_(float x) {
    return 1.0f - 2.0f * __builtin_amdgcn_rcpf(1.0f + fexp(2.0f * x));
}

__device__ __forceinline__ half8 ldfrag(const float* __restrict__ p) {
    half8 r;
#pragma unroll
    for (int j = 0; j < 8; ++j) r[j] = (f16)p[j];
    return r;
}

#define MFMA(a, b, c) __builtin_amdgcn_mfma_f32_16x16x32_f16((a), (b), (c), 0, 0, 0)

__global__ __launch_bounds__(NT, 4) void lstm_fused(
    const float* __restrict__ x,
    const float* __restrict__ Wih0, const float* __restrict__ Whh0,
    const float* __restrict__ bih0, const float* __restrict__ bhh0,
    const float* __restrict__ Wih1, const float* __restrict__ Whh1,
    const float* __restrict__ bih1, const float* __restrict__ bhh1,
    float* __restrict__ h2last)
{
    // LDS: 32 + 4 + 4 + 2 + 8 + 4 = 54 KB
    __shared__ __align__(16) f16 whh1k3[32 * 64 * 8];  // [ntile][lane][8]
    __shared__ __align__(16) f16 h1f[4 * 64 * 8];      // [ktile][lane][8] A-frag layout
    __shared__ __align__(16) f16 h2f[4 * 64 * 8];
    __shared__ __align__(16) f16 xf[2 * 64 * 8];       // [buf][lane][8] A-frag layout
    __shared__ float gpre[NB * 512];                   // [b][g] preactivations
    __shared__ float biasb[1024];                      // [0:512) layer0, [512:1024) layer1

    const int tid = threadIdx.x;
    const int lane = tid & 63;
    const int wv = tid >> 6;         // wave 0..15
    const int l15 = lane & 15;
    const int q = lane >> 4;         // quad 0..3
    const int b0 = blockIdx.x * NB;

    // ---- register B-fragments: B[n=lane&15][k=quad*8+j], wave owns ntiles {2wv, 2wv+1} ----
    half8 bWhh0[2][4], bWih1[2][4], bWhh1[2][3], bWih0[2];
#pragma unroll
    for (int ni = 0; ni < 2; ++ni) {
        const int nt = 2 * wv + ni;
        const int g = nt * 16 + l15;           // gate row
#pragma unroll
        for (int kt = 0; kt < 4; ++kt) {
            const int cb = kt * 32 + q * 8;    // k base
            bWhh0[ni][kt] = ldfrag(Whh0 + (size_t)g * H_ + cb);
            bWih1[ni][kt] = ldfrag(Wih1 + (size_t)g * H_ + cb);
            if (kt < 3) {
                bWhh1[ni][kt] = ldfrag(Whh1 + (size_t)g * H_ + cb);
            } else {
                half8 t3 = ldfrag(Whh1 + (size_t)g * H_ + cb);
                *(half8*)&whh1k3[(nt * 64 + lane) * 8] = t3;
            }
        }
        // Wih0: K=14 padded to 32 (one k-tile)
        half8 w0;
#pragma unroll
        for (int j = 0; j < 8; ++j) {
            int c = q * 8 + j;
            w0[j] = (c < D_) ? (f16)Wih0[(size_t)g * D_ + c] : (f16)0.0f;
        }
        bWih0[ni] = w0;
    }

    // ---- biases ----
    biasb[tid] = (tid < 512) ? (bih0[tid] + bhh0[tid])
                             : (bih1[tid - 512] + bhh1[tid - 512]);

    // ---- zero the A-frag state buffers ----
    ((unsigned int*)h1f)[tid] = 0u;     // 4 KB = 1024 dwords
    ((unsigned int*)h2f)[tid] = 0u;
    if (tid < 512) ((unsigned int*)xf)[tid] = 0u;
    __syncthreads();

    // ---- stage x_0 into xf[0] (A-frag layout: lane = b + 16*(d>>3), elem = d&7) ----
    if (tid < 64) {
        int b = tid >> 4, d = tid & 15;
        if (d < D_)
            xf[0 * 512 + (b + 16 * (d >> 3)) * 8 + (d & 7)] =
                (f16)x[((size_t)(b0 + b) * T_) * D_ + d];
    }

    // state-thread mapping (threads 0..511): (b, j)
    const int sb = tid >> 7, sj = tid & 127;
    const int hidx = (sj >> 5) * 512 + (sb + 16 * ((sj >> 3) & 3)) * 8 + (sj & 7);
    float cA = 0.0f, cB = 0.0f;

    __syncthreads();

    for (int t = 0; t < T_; ++t) {
        const int cur = t & 1, nxt = cur ^ 1;

        // ======== P1: layer-0 gate MFMAs ========
        floatx4 C0a = {0.f, 0.f, 0.f, 0.f}, C0b = {0.f, 0.f, 0.f, 0.f};
        {
            half8 ax = *(const half8*)&xf[cur * 512 + lane * 8];
            C0a = MFMA(ax, bWih0[0], C0a);
            C0b = MFMA(ax, bWih0[1], C0b);
#pragma unroll
            for (int kt = 0; kt < 4; ++kt) {
                half8 ah = *(const half8*)&h1f[kt * 512 + lane * 8];
                C0a = MFMA(ah, bWhh0[0][kt], C0a);
                C0b = MFMA(ah, bWhh0[1][kt], C0b);
            }
        }
        if (lane < 16) {
            const int g0 = (2 * wv) * 16 + lane, g1 = g0 + 16;
#pragma unroll
            for (int r = 0; r < 4; ++r) {
                gpre[r * 512 + g0] = C0a[r];
                gpre[r * 512 + g1] = C0b[r];
            }
        }
        __syncthreads();

        // ======== P2: layer-0 act + state update; others prefetch x ========
        if (tid < 512) {
            float pi = gpre[sb * 512 + sj]       + biasb[sj];
            float pf = gpre[sb * 512 + sj + 128] + biasb[sj + 128];
            float pg = gpre[sb * 512 + sj + 256] + biasb[sj + 256];
            float po = gpre[sb * 512 + sj + 384] + biasb[sj + 384];
            float i_ = sigm(pi), f_ = sigm(pf), g_ = tanh_(pg), o_ = sigm(po);
            cA = f_ * cA + i_ * g_;
            float h1 = o_ * tanh_(cA);
            h1f[hidx] = (f16)h1;
        } else if (tid < 576) {
            if (t + 1 < T_) {
                int i2 = tid - 512, b = i2 >> 4, d = i2 & 15;
                if (d < D_)
                    xf[nxt * 512 + (b + 16 * (d >> 3)) * 8 + (d & 7)] =
                        (f16)x[((size_t)(b0 + b) * T_ + (t + 1)) * D_ + d];
            }
        }
        __syncthreads();

        // ======== P3: layer-1 gate MFMAs ========
        floatx4 C1a = {0.f, 0.f, 0.f, 0.f}, C1b = {0.f, 0.f, 0.f, 0.f};
#pragma unroll
        for (int kt = 0; kt < 4; ++kt) {
            half8 a1 = *(const half8*)&h1f[kt * 512 + lane * 8];
            C1a = MFMA(a1, bWih1[0][kt], C1a);
            C1b = MFMA(a1, bWih1[1][kt], C1b);
        }
#pragma unroll
        for (int kt = 0; kt < 3; ++kt) {
            half8 a2 = *(const half8*)&h2f[kt * 512 + lane * 8];
            C1a = MFMA(a2, bWhh1[0][kt], C1a);
            C1b = MFMA(a2, bWhh1[1][kt], C1b);
        }
        {
            half8 a2 = *(const half8*)&h2f[3 * 512 + lane * 8];
            half8 w3a = *(const half8*)&whh1k3[((2 * wv) * 64 + lane) * 8];
            half8 w3b = *(const half8*)&whh1k3[((2 * wv + 1) * 64 + lane) * 8];
            C1a = MFMA(a2, w3a, C1a);
            C1b = MFMA(a2, w3b, C1b);
        }
        if (lane < 16) {
            const int g0 = (2 * wv) * 16 + lane, g1 = g0 + 16;
#pragma unroll
            for (int r = 0; r < 4; ++r) {
                gpre[r * 512 + g0] = C1a[r];
                gpre[r * 512 + g1] = C1b[r];
            }
        }
        __syncthreads();

        // ======== P4: layer-1 act + state update ========
        if (tid < 512) {
            float pi = gpre[sb * 512 + sj]       + biasb[512 + sj];
            float pf = gpre[sb * 512 + sj + 128] + biasb[512 + sj + 128];
            float pg = gpre[sb * 512 + sj + 256] + biasb[512 + sj + 256];
            float po = gpre[sb * 512 + sj + 384] + biasb[512 + sj + 384];
            float i_ = sigm(pi), f_ = sigm(pf), g_ = tanh_(pg), o_ = sigm(po);
            cB = f_ * cB + i_ * g_;
            float h2 = o_ * tanh_(cB);
            h2f[hidx] = (f16)h2;
            if (t == T_ - 1) h2last[(size_t)(b0 + sb) * H_ + sj] = h2;
        }
        __syncthreads();
    }
}

// batch-norm statistics over the batch dim: 1 block, 1024 threads
__global__ void bn_stats(const float* __restrict__ h2last, float* __restrict__ stats)
{
    __shared__ float red[2][8][128];
    const int tid = threadIdx.x;
    const int j = tid & 127, bs = tid >> 7;
    float s = 0.0f, ss = 0.0f;
    for (int bb = 0; bb < 128; ++bb) {
        float v = h2last[(size_t)(bb * 8 + bs) * H_ + j];
        s += v;
        ss += v * v;
    }
    red[0][bs][j] = s;
    red[1][bs][j] = ss;
    __syncthreads();
    if (tid < 128) {
        float S = 0.0f, SS = 0.0f;
#pragma unroll
        for (int k = 0; k < 8; ++k) { S += red[0][k][tid]; SS += red[1][k][tid]; }
        float mu = S * (1.0f / 1024.0f);
        float var = SS * (1.0f / 1024.0f) - mu * mu;
        stats[tid] = mu;
        stats[128 + tid] = __builtin_amdgcn_rsqf(var + 1e-5f);
    }
}

// normalize + MLP head: 8 blocks x 128 threads, one batch element per thread
__global__ void bn_mlp(const float* __restrict__ h2last, const float* __restrict__ stats,
                       const float* __restrict__ gamma, const float* __restrict__ beta,
                       const float* __restrict__ W1, const float* __restrict__ b1,
                       const float* __restrict__ W2, const float* __restrict__ b2,
                       float* __restrict__ out)
{
    __shared__ float W1T[128][33];
    __shared__ float mus[128], isds[128], gs[128], bts[128], w2s[32];
    const int tid = threadIdx.x;
    const int b = blockIdx.x * 128 + tid;

    for (int i = tid; i < 4096; i += 128) {
        int k = i >> 7, j = i & 127;
        W1T[j][k] = W1[i];
    }
    mus[tid] = stats[tid];
    isds[tid] = stats[128 + tid];
    gs[tid] = gamma[tid];
    bts[tid] = beta[tid];
    if (tid < 32) w2s[tid] = W2[tid];
    __syncthreads();

    float z[32];
#pragma unroll
    for (int k = 0; k < 32; ++k) z[k] = b1[k];

    for (int j = 0; j < 128; ++j) {
        float nv = (h2last[(size_t)b * H_ + j] - mus[j]) * isds[j] * gs[j] + bts[j];
#pragma unroll
        for (int k = 0; k < 32; ++k) z[k] += W1T[j][k] * nv;
    }
    float o = b2[0];
#pragma unroll
    for (int k = 0; k < 32; ++k) o += w2s[k] * fmaxf(z[k], 0.0f);
    out[b] = o;
}

extern "C" void kernel_launch(void* const* d_in, const int* in_sizes, int n_in,
                              void* d_out, int out_size, void* d_ws, size_t ws_size,
                              hipStream_t stream)
{
    const float* x    = (const float*)d_in[0];
    const float* Wih0 = (const float*)d_in[1];
    const float* Whh0 = (const float*)d_in[2];
    const float* bih0 = (const float*)d_in[3];
    const float* bhh0 = (const float*)d_in[4];
    const float* Wih1 = (const float*)d_in[5];
    const float* Whh1 = (const float*)d_in[6];
    const float* bih1 = (const float*)d_in[7];
    const float* bhh1 = (const float*)d_in[8];
    const float* gamma = (const float*)d_in[9];
    const float* beta  = (const float*)d_in[10];
    const float* W1 = (const float*)d_in[11];
    const float* b1 = (const float*)d_in[12];
    const float* W2 = (const float*)d_in[13];
    const float* b2 = (const float*)d_in[14];

    float* h2last = (float*)d_ws;              // 1024*128 floats = 512 KB
    float* stats  = h2last + (size_t)B_ * H_;  // 256 floats
    float* out = (float*)d_out;

    hipLaunchKernelGGL(lstm_fused, dim3(B_ / NB), dim3(NT), 0, stream,
                       x, Wih0, Whh0, bih0, bhh0, Wih1, Whh1, bih1, bhh1, h2last);
    hipLaunchKernelGGL(bn_stats, dim3(1), dim3(1024), 0, stream, h2last, stats);
    hipLaunchKernelGGL(bn_mlp, dim3(8), dim3(128), 0, stream,
                       h2last, stats, gamma, beta, W1, b1, W2, b2, out);
}

// Round 5
// 1201.897 us; speedup vs baseline: 99.0083x; 1.0985x over previous
//
#include <hip/hip_runtime.h>

// ForexLSTM: 2-layer LSTM (B=1024, T=512, D=14, H=128) + batchnorm-over-batch + MLP(128->32->1)
//
// Round 4: kill the DS-pipe bottleneck of R3 (16 waves redundantly re-reading h-frags +
// gpre LDS exchange = ~5000 DS cycles/step).
//   - 256 blocks x 512 threads (8 waves), NB=4 batches/block.
//   - Gate-grouped ntiles: wave w owns the (i,f,g,o) 16-col tiles of j-group [16w,16w+16).
//   - Weights are the MFMA *A* operand, h/x the *B* operand -> D[row=gate, col=batch]:
//     lane (n=lane&15, q=lane>>4) holds rows q*4+r = 4 consecutive gate rows for batch n.
//     With all 4 gate C-frags in one wave, activation + c-state update are IN-REGISTER
//     (no gpre exchange, no separate act phase). 2 barriers/step instead of 4.
//   - h state in LDS B-frag layout (dim16 = lane&15, k = quad*8+e, same bytes as R3's
//     validated layout); h write-back is one ds_write_b64 of 4 packed f16 per lane.
//   - bias0 folded into Wih0 via x-augmentation (x_aug[15] = 1.0); bias1 in 8 f16x2 regs.
//   - VGPR: Whh0 64 + Wih0 16 + Wih1 64 + Whh1(kt0-2) 48 = 192 weights; Whh1-kt3 in LDS.

#define B_ 1024
#define T_ 512
#define D_ 14
#define H_ 128
#define NB 4
#define NT 512

typedef _Float16 f16;
typedef _Float16 half4 __attribute__((ext_vector_type(4)));
typedef _Float16 half8 __attribute__((ext_vector_type(8)));
typedef _Float16 f16x2 __attribute__((ext_vector_type(2)));
typedef float floatx4 __attribute__((ext_vector_type(4)));

__device__ __forceinline__ float fexp(float x) {
    return __builtin_amdgcn_exp2f(x * 1.44269504088896f);
}
__device__ __forceinline__ float sigm(float x) {
    return __builtin_amdgcn_rcpf(1.0f + fexp(-x));
}
__device__ __forceinline__ float tanh_(float x) {
    return 1.0f - 2.0f * __builtin_amdgcn_rcpf(1.0f + fexp(2.0f * x));
}

__device__ __forceinline__ half8 ldfrag(const float* __restrict__ p) {
    half8 r;
#pragma unroll
    for (int j = 0; j < 8; ++j) r[j] = (f16)p[j];
    return r;
}

#define MFMA(a, b, c) __builtin_amdgcn_mfma_f32_16x16x32_f16((a), (b), (c), 0, 0, 0)

__global__ __launch_bounds__(NT, 2) void lstm_fused(
    const float* __restrict__ x,
    const float* __restrict__ Wih0, const float* __restrict__ Whh0,
    const float* __restrict__ bih0, const float* __restrict__ bhh0,
    const float* __restrict__ Wih1, const float* __restrict__ Whh1,
    const float* __restrict__ bih1, const float* __restrict__ bhh1,
    float* __restrict__ h2last)
{
    // LDS: 32 + 8 + 8 + 1 = 49 KB
    __shared__ __align__(16) f16 whh1k3[32][64][8];   // Whh1 kt3 A-frags, [ntile][lane][e]
    __shared__ __align__(16) f16 h1f[2][4][64][8];    // [buf][kt][lane][e] B-frag layout
    __shared__ __align__(16) f16 h2f[2][4][64][8];
    __shared__ __align__(16) f16 xf[64][8];           // x_aug B-frag (K=16: 14 x, 0, 1.0)

    const int tid = threadIdx.x;
    const int lane = tid & 63;
    const int wv = tid >> 6;        // wave 0..7 = j-group
    const int n = lane & 15;        // batch column (valid < NB)
    const int q = lane >> 4;        // quad -> rows q*4+r
    const int b0 = blockIdx.x * NB;
    const int jg = wv * 16;         // j-group base
    // h write-back target: j = jg + q*4 + r  ->  kt=wv>>1, q'=(wv&1)*2+(q>>1), e=(q&1)*4+r
    const int ktw = wv >> 1;
    const int qw = (wv & 1) * 2 + (q >> 1);
    const int eb = (q & 1) * 4;

    // ---- weights into registers as A-frags: A[m=lane&15][k=q*8+e] ----
    half8 aWhh0[4][4], aWih1[4][4], aWhh1[4][3], aWih0[4];
    f16x2 b1p[4][2];   // layer-1 bias for rows q*4+{0..3}, per gate, packed f16

#pragma unroll
    for (int ni = 0; ni < 4; ++ni) {
        const int g = ni * 128 + jg + n;           // gate row for this lane's A-frags
#pragma unroll
        for (int kt = 0; kt < 4; ++kt) {
            const int cb = kt * 32 + q * 8;
            aWhh0[ni][kt] = ldfrag(Whh0 + (size_t)g * H_ + cb);
            aWih1[ni][kt] = ldfrag(Wih1 + (size_t)g * H_ + cb);
            if (kt < 3) {
                aWhh1[ni][kt] = ldfrag(Whh1 + (size_t)g * H_ + cb);
            } else {
                half8 t3 = ldfrag(Whh1 + (size_t)g * H_ + cb);
                *(half8*)&whh1k3[ni * 8 + wv][lane][0] = t3;
            }
        }
        // Wih0 augmented: k<14 = W, k==15 = bias0 (bih0+bhh0), k==14 = 0
        half8 w0;
#pragma unroll
        for (int e = 0; e < 8; ++e) {
            int k = q * 8 + e;
            if (k < D_)       w0[e] = (f16)Wih0[(size_t)g * D_ + k];
            else if (k == 15) w0[e] = (f16)(bih0[g] + bhh0[g]);
            else              w0[e] = (f16)0.0f;
        }
        aWih0[ni] = w0;
        // bias1 for rows (ni*128 + jg + q*4 + r)
        const int gb = ni * 128 + jg + q * 4;
        f16x2 p0, p1;
        p0[0] = (f16)(bih1[gb]     + bhh1[gb]);
        p0[1] = (f16)(bih1[gb + 1] + bhh1[gb + 1]);
        p1[0] = (f16)(bih1[gb + 2] + bhh1[gb + 2]);
        p1[1] = (f16)(bih1[gb + 3] + bhh1[gb + 3]);
        b1p[ni][0] = p0;
        b1p[ni][1] = p1;
    }

    // ---- zero state buffers (h1f+h2f = 4096 dwords, xf = 128 dwords) ----
#pragma unroll
    for (int i = 0; i < 4; ++i) {
        ((unsigned int*)h1f)[tid + i * 512] = 0u;
        ((unsigned int*)h2f)[tid + i * 512] = 0u;
    }
    if (tid < 128) ((unsigned int*)xf)[tid] = 0u;
    __syncthreads();

    // ---- stage x_aug(0): lane slot tid = nn + 16*kq holds k = kq*8+e ----
    if (tid < 64) {
        int nn = tid & 15, kq = tid >> 4;
        if (nn < NB) {
            half8 v;
#pragma unroll
            for (int e = 0; e < 8; ++e) {
                int k = kq * 8 + e;
                float xv = (k < D_) ? x[(size_t)(b0 + nn) * T_ * D_ + k] : (k == 15 ? 1.0f : 0.0f);
                v[e] = (f16)xv;
            }
            *(half8*)&xf[tid][0] = v;
        }
    }

    floatx4 c1 = {0.f, 0.f, 0.f, 0.f}, c2 = {0.f, 0.f, 0.f, 0.f};
    __syncthreads();

    for (int t = 0; t < T_; ++t) {
        const int cur = t & 1, nxt = cur ^ 1;

        // x(t+1) prefetch into a register (consumed at end of P2)
        float xp = 0.0f;
        if (tid < NB * D_ && (t + 1) < T_)
            xp = x[(size_t)(b0 + (tid & 3)) * T_ * D_ + (size_t)(t + 1) * D_ + (tid >> 2)];

        // ======== P1: layer-0 gates + in-register act/state ========
        floatx4 C[4];
#pragma unroll
        for (int ni = 0; ni < 4; ++ni) C[ni] = floatx4{0.f, 0.f, 0.f, 0.f};
        {
            half8 bx = *(const half8*)&xf[lane][0];
#pragma unroll
            for (int ni = 0; ni < 4; ++ni) C[ni] = MFMA(aWih0[ni], bx, C[ni]);
#pragma unroll
            for (int kt = 0; kt < 4; ++kt) {
                half8 bh = *(const half8*)&h1f[cur][kt][lane][0];
#pragma unroll
                for (int ni = 0; ni < 4; ++ni) C[ni] = MFMA(aWhh0[ni][kt], bh, C[ni]);
            }
        }
        {
            half4 hp;
#pragma unroll
            for (int r = 0; r < 4; ++r) {
                float i_ = sigm(C[0][r]);
                float f_ = sigm(C[1][r]);
                float g_ = tanh_(C[2][r]);
                float o_ = sigm(C[3][r]);
                c1[r] = f_ * c1[r] + i_ * g_;
                hp[r] = (f16)(o_ * tanh_(c1[r]));
            }
            if (n < NB) *(half4*)&h1f[nxt][ktw][n + 16 * qw][eb] = hp;
        }
        __syncthreads();

        // ======== P2: layer-1 gates + in-register act/state ========
#pragma unroll
        for (int ni = 0; ni < 4; ++ni) C[ni] = floatx4{0.f, 0.f, 0.f, 0.f};
#pragma unroll
        for (int kt = 0; kt < 4; ++kt) {
            half8 bh = *(const half8*)&h1f[nxt][kt][lane][0];    // h1(t)
#pragma unroll
            for (int ni = 0; ni < 4; ++ni) C[ni] = MFMA(aWih1[ni][kt], bh, C[ni]);
        }
#pragma unroll
        for (int kt = 0; kt < 3; ++kt) {
            half8 bh = *(const half8*)&h2f[cur][kt][lane][0];    // h2(t-1)
#pragma unroll
            for (int ni = 0; ni < 4; ++ni) C[ni] = MFMA(aWhh1[ni][kt], bh, C[ni]);
        }
        {
            half8 bh = *(const half8*)&h2f[cur][3][lane][0];
#pragma unroll
            for (int ni = 0; ni < 4; ++ni) {
                half8 aw = *(const half8*)&whh1k3[ni * 8 + wv][lane][0];
                C[ni] = MFMA(aw, bh, C[ni]);
            }
        }
        {
            half4 hp;
            floatx4 hv;
#pragma unroll
            for (int r = 0; r < 4; ++r) {
                float pi = C[0][r] + (float)b1p[0][r >> 1][r & 1];
                float pf = C[1][r] + (float)b1p[1][r >> 1][r & 1];
                float pg = C[2][r] + (float)b1p[2][r >> 1][r & 1];
                float po = C[3][r] + (float)b1p[3][r >> 1][r & 1];
                float i_ = sigm(pi), f_ = sigm(pf), g_ = tanh_(pg), o_ = sigm(po);
                c2[r] = f_ * c2[r] + i_ * g_;
                hv[r] = o_ * tanh_(c2[r]);
                hp[r] = (f16)hv[r];
            }
            if (n < NB) {
                *(half4*)&h2f[nxt][ktw][n + 16 * qw][eb] = hp;
                if (t == T_ - 1) {
#pragma unroll
                    for (int r = 0; r < 4; ++r)
                        h2last[(size_t)(b0 + n) * H_ + jg + q * 4 + r] = hv[r];
                }
            }
        }
        // restage x(t+1) (k slots 0..13 only; 14/15 stay 0/1 from init)
        if (tid < NB * D_ && (t + 1) < T_) {
            int k = tid >> 2;
            xf[(tid & 3) + 16 * (k >> 3)][k & 7] = (f16)xp;
        }
        __syncthreads();
    }
}

// batch-norm statistics over the batch dim: 1 block, 1024 threads
__global__ void bn_stats(const float* __restrict__ h2last, float* __restrict__ stats)
{
    __shared__ float red[2][8][128];
    const int tid = threadIdx.x;
    const int j = tid & 127, bs = tid >> 7;
    float s = 0.0f, ss = 0.0f;
    for (int bb = 0; bb < 128; ++bb) {
        float v = h2last[(size_t)(bb * 8 + bs) * H_ + j];
        s += v;
        ss += v * v;
    }
    red[0][bs][j] = s;
    red[1][bs][j] = ss;
    __syncthreads();
    if (tid < 128) {
        float S = 0.0f, SS = 0.0f;
#pragma unroll
        for (int k = 0; k < 8; ++k) { S += red[0][k][tid]; SS += red[1][k][tid]; }
        float mu = S * (1.0f / 1024.0f);
        float var = SS * (1.0f / 1024.0f) - mu * mu;
        stats[tid] = mu;
        stats[128 + tid] = __builtin_amdgcn_rsqf(var + 1e-5f);
    }
}

// normalize + MLP head: 8 blocks x 128 threads, one batch element per thread
__global__ void bn_mlp(const float* __restrict__ h2last, const float* __restrict__ stats,
                       const float* __restrict__ gamma, const float* __restrict__ beta,
                       const float* __restrict__ W1, const float* __restrict__ b1,
                       const float* __restrict__ W2, const float* __restrict__ b2,
                       float* __restrict__ out)
{
    __shared__ float W1T[128][33];
    __shared__ float mus[128], isds[128], gs[128], bts[128], w2s[32];
    const int tid = threadIdx.x;
    const int b = blockIdx.x * 128 + tid;

    for (int i = tid; i < 4096; i += 128) {
        int k = i >> 7, j = i & 127;
        W1T[j][k] = W1[i];
    }
    mus[tid] = stats[tid];
    isds[tid] = stats[128 + tid];
    gs[tid] = gamma[tid];
    bts[tid] = beta[tid];
    if (tid < 32) w2s[tid] = W2[tid];
    __syncthreads();

    float z[32];
#pragma unroll
    for (int k = 0; k < 32; ++k) z[k] = b1[k];

    for (int j = 0; j < 128; ++j) {
        float nv = (h2last[(size_t)b * H_ + j] - mus[j]) * isds[j] * gs[j] + bts[j];
#pragma unroll
        for (int k = 0; k < 32; ++k) z[k] += W1T[j][k] * nv;
    }
    float o = b2[0];
#pragma unroll
    for (int k = 0; k < 32; ++k) o += w2s[k] * fmaxf(z[k], 0.0f);
    out[b] = o;
}

extern "C" void kernel_launch(void* const* d_in, const int* in_sizes, int n_in,
                              void* d_out, int out_size, void* d_ws, size_t ws_size,
                              hipStream_t stream)
{
    const float* x    = (const float*)d_in[0];
    const float* Wih0 = (const float*)d_in[1];
    const float* Whh0 = (const float*)d_in[2];
    const float* bih0 = (const float*)d_in[3];
    const float* bhh0 = (const float*)d_in[4];
    const float* Wih1 = (const float*)d_in[5];
    const float* Whh1 = (const float*)d_in[6];
    const float* bih1 = (const float*)d_in[7];
    const float* bhh1 = (const float*)d_in[8];
    const float* gamma = (const float*)d_in[9];
    const float* beta  = (const float*)d_in[10];
    const float* W1 = (const float*)d_in[11];
    const float* b1 = (const float*)d_in[12];
    const float* W2 = (const float*)d_in[13];
    const float* b2 = (const float*)d_in[14];

    float* h2last = (float*)d_ws;              // 1024*128 floats = 512 KB
    float* stats  = h2last + (size_t)B_ * H_;  // 256 floats
    float* out = (float*)d_out;

    hipLaunchKernelGGL(lstm_fused, dim3(B_ / NB), dim3(NT), 0, stream,
                       x, Wih0, Whh0, bih0, bhh0, Wih1, Whh1, bih1, bhh1, h2last);
    hipLaunchKernelGGL(bn_stats, dim3(1), dim3(1024), 0, stream, h2last, stats);
    hipLaunchKernelGGL(bn_mlp, dim3(8), dim3(128), 0, stream,
                       h2last, stats, gamma, beta, W1, b1, W2, b2, out);
}